// Round 1
// baseline (820.312 us; speedup 1.0000x reference)
//
#include <hip/hip_runtime.h>
#include <math.h>

#define EPS 1e-5f
#define SQRT3F 1.7320508075688772f

__device__ __forceinline__ float wsum64(float x) {
#pragma unroll
    for (int o = 32; o > 0; o >>= 1) x += __shfl_xor(x, o, 64);
    return x;
}
__device__ __forceinline__ float wmax32(float x) {
#pragma unroll
    for (int o = 16; o > 0; o >>= 1) x = fmaxf(x, __shfl_xor(x, o, 32));
    return x;
}
__device__ __forceinline__ float sigm(float x) { return 1.f / (1.f + __expf(-x)); }
__device__ __forceinline__ float siluf(float x) { return x * sigm(x); }

// ---------------------------------------------------------------------------
// Kernel 1: per-node preprocessing.
// feats_ln = LN(feats); equ_ln = equ_layer_norm(equ);
// feats1 = feats_ln @ inv_fc_w + b (N x 32); equ1 = equ_ln @ equ_fc_w (N x 4 x 32)
// One wave (64 lanes) per node, 4 nodes per 256-thread block.
// ---------------------------------------------------------------------------
__global__ __launch_bounds__(256) void node_pre(
    int N,
    const float* __restrict__ feats, const float* __restrict__ equ,
    const float* __restrict__ ln1_w, const float* __restrict__ ln1_b,
    const float* __restrict__ eqn1_w, const float* __restrict__ eqn1_b,
    const float* __restrict__ inv_fc_w, const float* __restrict__ inv_fc_b,
    const float* __restrict__ equ_fc_w,
    float* __restrict__ feats_ln, float* __restrict__ equ_ln,
    float* __restrict__ feats1, float* __restrict__ equ1)
{
    __shared__ float fl_s[4][128];
    __shared__ float el_s[4][128];
    const int w = threadIdx.x >> 6;
    const int lane = threadIdx.x & 63;
    const int n = blockIdx.x * 4 + w;
    const bool act = n < N;
    const int c = lane & 31;

    // ---- feats LayerNorm (128 elems, 2 per lane) ----
    float x0 = 0.f, x1 = 0.f;
    if (act) { x0 = feats[n * 128 + lane]; x1 = feats[n * 128 + 64 + lane]; }
    float s  = wsum64(x0 + x1);
    float sq = wsum64(x0 * x0 + x1 * x1);
    float mu = s * (1.f / 128.f);
    float var = sq * (1.f / 128.f) - mu * mu;
    float rs = rsqrtf(var + EPS);
    float y0 = (x0 - mu) * rs * ln1_w[lane] + ln1_b[lane];
    float y1 = (x1 - mu) * rs * ln1_w[64 + lane] + ln1_b[64 + lane];
    if (act) { feats_ln[n * 128 + lane] = y0; feats_ln[n * 128 + 64 + lane] = y1; }
    fl_s[w][lane] = y0; fl_s[w][64 + lane] = y1;

    // ---- equ layer norm ----
    // layout equ[n][l][c], l=0..3. lane<32: a=row0, b=row2; lane>=32: a=row1, b=row3.
    float a = 0.f, b = 0.f;
    if (act) { a = equ[n * 128 + lane]; b = equ[n * 128 + 64 + lane]; }
    // l=0 segment: centered, norm over 32
    float a0 = (lane < 32) ? a : 0.f;
    float m0 = wsum64(a0) * (1.f / 32.f);
    float f0 = a0 - m0;
    float n0 = wsum64((lane < 32) ? f0 * f0 : 0.f) * (1.f / 32.f);
    float rs0 = rsqrtf(n0 + EPS);
    // l=1 segment (rows 1..3): norm over 96
    float sq1 = ((lane >= 32) ? a * a : 0.f) + b * b;
    float n1 = wsum64(sq1) * (1.f / 96.f);
    float rs1 = rsqrtf(n1 + EPS);
    float w1c = eqn1_w[32 + c];
    float ea = (lane < 32) ? (f0 * rs0 * eqn1_w[c] + eqn1_b[c]) : (a * rs1 * w1c);
    float eb = b * rs1 * w1c;
    if (act) { equ_ln[n * 128 + lane] = ea; equ_ln[n * 128 + 64 + lane] = eb; }
    el_s[w][lane] = ea; el_s[w][64 + lane] = eb;

    __syncthreads();
    if (!act) return;

    // ---- feats1 = feats_ln @ inv_fc_w (128x32) + b : lanes 0..31 ----
    if (lane < 32) {
        float acc = inv_fc_b[lane];
#pragma unroll 8
        for (int k = 0; k < 128; k++) acc += fl_s[w][k] * inv_fc_w[k * 32 + lane];
        feats1[n * 32 + lane] = acc;
    }
    // ---- equ1 = equ_ln @ equ_fc_w (rows independent): 2 outputs per lane ----
    {
        const int l = lane >> 5;
        float acc = 0.f, acc2 = 0.f;
#pragma unroll 8
        for (int k = 0; k < 32; k++) {
            float wv = equ_fc_w[k * 32 + c];
            acc  += el_s[w][l * 32 + k] * wv;
            acc2 += el_s[w][(l + 2) * 32 + k] * wv;
        }
        equ1[n * 128 + lane] = acc;
        equ1[n * 128 + 64 + lane] = acc2;
    }
}

// ---------------------------------------------------------------------------
// Kernel 2: per-edge messages + scatter-add. Half-wave (32 lanes) per edge,
// 8 edges per 256-thread block, grid-stride over edge chunks.
// inv_fc_1_w (96x128, 48KB) staged in LDS once per block.
// ---------------------------------------------------------------------------
__global__ __launch_bounds__(256) void edge_kernel(
    int E,
    const int* __restrict__ nb, const float* __restrict__ points,
    const float* __restrict__ feats1, const float* __restrict__ equ1,
    const float* __restrict__ Wl0, const float* __restrict__ bl0,
    const float* __restrict__ We2g, const float* __restrict__ Winvg,
    const float* __restrict__ binvg,
    float* __restrict__ inv_acc, float* __restrict__ equ_acc, float* __restrict__ cnt)
{
    __shared__ float Winv[96 * 128];   // 48 KB
    __shared__ float We2[32 * 32];     // 4 KB
    __shared__ float binv[128];
    __shared__ float dots[8][64];      // dot1 | dot2 per edge slot
    __shared__ float invin[8][96];     // s_feats | t_feats | equ_l0
    __shared__ float sequ[8][128];     // s_equ rows

    for (int i = threadIdx.x; i < 96 * 128; i += 256) Winv[i] = Winvg[i];
    for (int i = threadIdx.x; i < 32 * 32; i += 256) We2[i] = We2g[i];
    if (threadIdx.x < 128) binv[threadIdx.x] = binvg[threadIdx.x];
    __syncthreads();

    const int slot = threadIdx.x >> 5;
    const int c = threadIdx.x & 31;
    const int nchunk = (E + 7) / 8;

    for (int chunk = blockIdx.x; chunk < nchunk; chunk += gridDim.x) {
        const int e = chunk * 8 + slot;
        const bool act = e < E;
        int dst = 0;
        if (act) {
            const int src = nb[e];
            dst = nb[E + e];
            float se0 = equ1[src * 128 + c];
            float se1 = equ1[src * 128 + 32 + c];
            float se2 = equ1[src * 128 + 64 + c];
            float se3 = equ1[src * 128 + 96 + c];
            float te0 = equ1[dst * 128 + c];
            float te1 = equ1[dst * 128 + 32 + c];
            float te2 = equ1[dst * 128 + 64 + c];
            float te3 = equ1[dst * 128 + 96 + c];
            float sh1 = SQRT3F * (points[src * 3 + 0] - points[dst * 3 + 0]);
            float sh2 = SQRT3F * (points[src * 3 + 1] - points[dst * 3 + 1]);
            float sh3 = SQRT3F * (points[src * 3 + 2] - points[dst * 3 + 2]);
            dots[slot][c]      = se0 * te0 + se1 * te1 + se2 * te2 + se3 * te3;
            dots[slot][32 + c] = se0 + se1 * sh1 + se2 * sh2 + se3 * sh3;
            invin[slot][c]      = feats1[src * 32 + c];
            invin[slot][32 + c] = feats1[dst * 32 + c];
            sequ[slot][c] = se0; sequ[slot][32 + c] = se1;
            sequ[slot][64 + c] = se2; sequ[slot][96 + c] = se3;
        }
        __syncthreads();
        if (act) {
            // equ_l0 = silu([dot1,dot2] @ fc_l0_w + b)
            float acc = bl0[c];
#pragma unroll 8
            for (int k = 0; k < 64; k++) acc += dots[slot][k] * Wl0[k * 32 + c];
            invin[slot][64 + c] = siluf(acc);
        }
        __syncthreads();
        if (act) {
            // inv_message = silu(invin @ inv_fc_1_w + b), lane c owns outs c+32j
            float m0 = binv[c], m1 = binv[32 + c], m2 = binv[64 + c], m3 = binv[96 + c];
#pragma unroll 4
            for (int k = 0; k < 96; k++) {
                float x = invin[slot][k];
                m0 += x * Winv[k * 128 + c];
                m1 += x * Winv[k * 128 + 32 + c];
                m2 += x * Winv[k * 128 + 64 + c];
                m3 += x * Winv[k * 128 + 96 + c];
            }
            m0 = siluf(m0); m1 = siluf(m1); m2 = siluf(m2); m3 = siluf(m3);

            // equ_message = [equ_l0, s_equ rows 1..3] @ equ_fc_2_w
            float e0 = 0.f, e1 = 0.f, e2 = 0.f, e3 = 0.f;
#pragma unroll 8
            for (int k = 0; k < 32; k++) {
                float wv = We2[k * 32 + c];
                e0 += invin[slot][64 + k] * wv;
                e1 += sequ[slot][32 + k] * wv;
                e2 += sequ[slot][64 + k] * wv;
                e3 += sequ[slot][96 + k] * wv;
            }
            // nb_cnt
            float mx = fmaxf(fmaxf(m0, m1), fmaxf(m2, m3));
            mx = wmax32(mx);
            if (c == 0 && mx > 0.f) atomicAdd(&cnt[dst], 1.0f);
            float* ia = &inv_acc[dst * 128];
            atomicAdd(ia + c, m0); atomicAdd(ia + 32 + c, m1);
            atomicAdd(ia + 64 + c, m2); atomicAdd(ia + 96 + c, m3);
            float* ea = &equ_acc[dst * 128];
            atomicAdd(ea + c, e0); atomicAdd(ea + 32 + c, e1);
            atomicAdd(ea + 64 + c, e2); atomicAdd(ea + 96 + c, e3);
        }
        __syncthreads();
    }
}

// ---------------------------------------------------------------------------
// Kernel 3: per-node postprocessing. One wave per node, 4 nodes per block.
// ---------------------------------------------------------------------------
__global__ __launch_bounds__(256) void node_post(
    int N,
    const float* __restrict__ feats_ln, const float* __restrict__ equ_ln,
    const float* __restrict__ inv_acc, const float* __restrict__ equ_acc,
    const float* __restrict__ cnt,
    const float* __restrict__ ffn_ln_w, const float* __restrict__ ffn_ln_b,
    const float* __restrict__ W1, const float* __restrict__ b1,
    const float* __restrict__ W2, const float* __restrict__ b2,
    const float* __restrict__ eqn2_w, const float* __restrict__ eqn2_b,
    const float* __restrict__ fe1, const float* __restrict__ gate_w,
    const float* __restrict__ fe2,
    float* __restrict__ out_inv, float* __restrict__ out_equ)
{
    __shared__ float h_s[4][128];
    __shared__ float r_s[4][128];
    __shared__ float e_s[4][128];
    __shared__ float g_s[4][128];
    __shared__ float aft_s[4][64];
    __shared__ float gg_s[4][128];

    const int w = threadIdx.x >> 6;
    const int lane = threadIdx.x & 63;
    const int n = blockIdx.x * 4 + w;
    const bool act = n < N;
    const int c = lane & 31;

    float nbn = 1.f;
    if (act) nbn = 1.f + cnt[n];
    const float inv_nbn = 1.f / nbn;

    // inv_new (pre-FFN)
    float inv0 = 0.f, inv1 = 0.f;
    if (act) {
        inv0 = (inv_acc[n * 128 + lane] + feats_ln[n * 128 + lane]) * inv_nbn;
        inv1 = (inv_acc[n * 128 + 64 + lane] + feats_ln[n * 128 + 64 + lane]) * inv_nbn;
    }
    // LN
    float s  = wsum64(inv0 + inv1);
    float sq = wsum64(inv0 * inv0 + inv1 * inv1);
    float mu = s * (1.f / 128.f);
    float var = sq * (1.f / 128.f) - mu * mu;
    float rs = rsqrtf(var + EPS);
    h_s[w][lane]      = (inv0 - mu) * rs * ffn_ln_w[lane] + ffn_ln_b[lane];
    h_s[w][64 + lane] = (inv1 - mu) * rs * ffn_ln_w[64 + lane] + ffn_ln_b[64 + lane];

    // equ_new (pre-gate)
    float en_a = 0.f, en_b = 0.f;
    if (act) {
        en_a = (equ_acc[n * 128 + lane] + equ_ln[n * 128 + lane]) * inv_nbn;
        en_b = (equ_acc[n * 128 + 64 + lane] + equ_ln[n * 128 + 64 + lane]) * inv_nbn;
    }
    // eqn2 layer norm
    float a0 = (lane < 32) ? en_a : 0.f;
    float m0 = wsum64(a0) * (1.f / 32.f);
    float f0 = a0 - m0;
    float n0 = wsum64((lane < 32) ? f0 * f0 : 0.f) * (1.f / 32.f);
    float rs0 = rsqrtf(n0 + EPS);
    float sq1 = ((lane >= 32) ? en_a * en_a : 0.f) + en_b * en_b;
    float n1 = wsum64(sq1) * (1.f / 96.f);
    float rs1 = rsqrtf(n1 + EPS);
    float w1c = eqn2_w[32 + c];
    e_s[w][lane]      = (lane < 32) ? (f0 * rs0 * eqn2_w[c] + eqn2_b[c]) : (en_a * rs1 * w1c);
    e_s[w][64 + lane] = en_b * rs1 * w1c;

    __syncthreads();

    // FFN layer 1: r = relu(h @ W1 + b1), 2 outputs/lane
    {
        float acc0 = b1[lane], acc1 = b1[64 + lane];
#pragma unroll 4
        for (int k = 0; k < 128; k++) {
            float x = h_s[w][k];
            acc0 += x * W1[k * 128 + lane];
            acc1 += x * W1[k * 128 + 64 + lane];
        }
        r_s[w][lane] = fmaxf(acc0, 0.f);
        r_s[w][64 + lane] = fmaxf(acc1, 0.f);
    }
    // g = eqn2_out @ fe1 (rows independent), 2 outputs/lane
    {
        const int l = lane >> 5;
        float acc = 0.f, acc2 = 0.f;
#pragma unroll 8
        for (int k = 0; k < 32; k++) {
            float wv = fe1[k * 32 + c];
            acc  += e_s[w][l * 32 + k] * wv;
            acc2 += e_s[w][(l + 2) * 32 + k] * wv;
        }
        g_s[w][lane] = acc;
        g_s[w][64 + lane] = acc2;
    }
    __syncthreads();

    // FFN layer 2 + residual
    if (act) {
        float acc0 = b2[lane], acc1 = b2[64 + lane];
#pragma unroll 4
        for (int k = 0; k < 128; k++) {
            float x = r_s[w][k];
            acc0 += x * W2[k * 128 + lane];
            acc1 += x * W2[k * 128 + 64 + lane];
        }
        out_inv[n * 128 + lane] = acc0 + inv0;
        out_inv[n * 128 + 64 + lane] = acc1 + inv1;
    }
    // gate pre-activation: after[j] = g_row0 @ gate_w[:, j], one j per lane
    {
        float acc = 0.f;
#pragma unroll 8
        for (int k = 0; k < 32; k++) acc += g_s[w][k] * gate_w[k * 64 + lane];
        aft_s[w][lane] = acc;
    }
    __syncthreads();

    // gated rows
    {
        const int l = lane >> 5;
        float mult = sigm(aft_s[w][32 + c]);
        float G0 = (l == 0) ? siluf(aft_s[w][c]) : (g_s[w][32 + c] * mult);
        float G1 = g_s[w][64 + lane] * mult;
        gg_s[w][lane] = G0;
        gg_s[w][64 + lane] = G1;
    }
    __syncthreads();

    // final: out_equ = G @ fe2 + equ_new
    if (act) {
        const int l = lane >> 5;
        float acc = 0.f, acc2 = 0.f;
#pragma unroll 8
        for (int k = 0; k < 32; k++) {
            float wv = fe2[k * 32 + c];
            acc  += gg_s[w][l * 32 + k] * wv;
            acc2 += gg_s[w][(l + 2) * 32 + k] * wv;
        }
        out_equ[n * 128 + lane] = acc + en_a;
        out_equ[n * 128 + 64 + lane] = acc2 + en_b;
    }
}

// ---------------------------------------------------------------------------
extern "C" void kernel_launch(void* const* d_in, const int* in_sizes, int n_in,
                              void* d_out, int out_size, void* d_ws, size_t ws_size,
                              hipStream_t stream)
{
    const float* feats     = (const float*)d_in[0];
    const float* equ       = (const float*)d_in[1];
    const float* points    = (const float*)d_in[2];
    const int*   neighbors = (const int*)d_in[3];
    const float* ln1_w     = (const float*)d_in[4];
    const float* ln1_b     = (const float*)d_in[5];
    const float* eqn1_w    = (const float*)d_in[6];
    const float* eqn1_b    = (const float*)d_in[7];
    const float* inv_fc_w  = (const float*)d_in[8];
    const float* inv_fc_b  = (const float*)d_in[9];
    const float* equ_fc_w  = (const float*)d_in[10];
    const float* fc_l0_w   = (const float*)d_in[11];
    const float* fc_l0_b   = (const float*)d_in[12];
    const float* equ_fc_2_w= (const float*)d_in[13];
    const float* inv_fc_1_w= (const float*)d_in[14];
    const float* inv_fc_1_b= (const float*)d_in[15];
    const float* ffn_ln_w  = (const float*)d_in[16];
    const float* ffn_ln_b  = (const float*)d_in[17];
    const float* ffn_w1    = (const float*)d_in[18];
    const float* ffn_b1    = (const float*)d_in[19];
    const float* ffn_w2    = (const float*)d_in[20];
    const float* ffn_b2    = (const float*)d_in[21];
    const float* eqn2_w    = (const float*)d_in[22];
    const float* eqn2_b    = (const float*)d_in[23];
    const float* fe1_w     = (const float*)d_in[24];
    const float* gate_w    = (const float*)d_in[25];
    const float* fe2_w     = (const float*)d_in[26];

    const int N = in_sizes[0] / 128;
    const int E = in_sizes[3] / 2;

    float* ws = (float*)d_ws;
    float* feats_ln = ws;                      // N*128
    float* equ_ln   = feats_ln + (size_t)N * 128;  // N*128
    float* feats1   = equ_ln + (size_t)N * 128;    // N*32
    float* equ1     = feats1 + (size_t)N * 32;     // N*128
    float* inv_acc  = equ1 + (size_t)N * 128;      // N*128  (zeroed)
    float* equ_acc  = inv_acc + (size_t)N * 128;   // N*128  (zeroed)
    float* cnt      = equ_acc + (size_t)N * 128;   // N      (zeroed)

    hipMemsetAsync(inv_acc, 0, (size_t)N * 257 * sizeof(float), stream);

    node_pre<<<(N + 3) / 4, 256, 0, stream>>>(
        N, feats, equ, ln1_w, ln1_b, eqn1_w, eqn1_b,
        inv_fc_w, inv_fc_b, equ_fc_w,
        feats_ln, equ_ln, feats1, equ1);

    edge_kernel<<<512, 256, 0, stream>>>(
        E, neighbors, points, feats1, equ1,
        fc_l0_w, fc_l0_b, equ_fc_2_w, inv_fc_1_w, inv_fc_1_b,
        inv_acc, equ_acc, cnt);

    float* out_inv = (float*)d_out;
    float* out_equ = out_inv + (size_t)N * 128;
    node_post<<<(N + 3) / 4, 256, 0, stream>>>(
        N, feats_ln, equ_ln, inv_acc, equ_acc, cnt,
        ffn_ln_w, ffn_ln_b, ffn_w1, ffn_b1, ffn_w2, ffn_b2,
        eqn2_w, eqn2_b, fe1_w, gate_w, fe2_w,
        out_inv, out_equ);
}

// Round 2
// 589.020 us; speedup vs baseline: 1.3927x; 1.3927x over previous
//
#include <hip/hip_runtime.h>
#include <math.h>

#define EPS 1e-5f
#define SQRT3F 1.7320508075688772f

__device__ __forceinline__ float wsum64(float x) {
#pragma unroll
    for (int o = 32; o > 0; o >>= 1) x += __shfl_xor(x, o, 64);
    return x;
}
__device__ __forceinline__ float wmax32(float x) {
#pragma unroll
    for (int o = 16; o > 0; o >>= 1) x = fmaxf(x, __shfl_xor(x, o, 32));
    return x;
}
__device__ __forceinline__ float sigm(float x) { return 1.f / (1.f + __expf(-x)); }
__device__ __forceinline__ float siluf(float x) { return x * sigm(x); }

// ---------------------------------------------------------------------------
// Kernel 1: per-node preprocessing.
// feats_ln = LN(feats); equ_ln = equ_layer_norm(equ)
// feats1 = feats_ln @ inv_fc_w + b          (kept in LDS only)
// equ1t[n][c][l] = (equ_ln @ equ_fc_w)[l][c]   (transposed for edge gathers)
// PsP[n][c][j] = (feats1 @ Winv[0:32])[j*32+c]   (src part of inv_fc_1)
// PtP[n][c][j] = (feats1 @ Winv[32:64])[j*32+c]  (dst part)
// One wave per node, 4 nodes per 256-thread block.
// ---------------------------------------------------------------------------
__global__ __launch_bounds__(256) void node_pre(
    int N,
    const float* __restrict__ feats, const float* __restrict__ equ,
    const float* __restrict__ ln1_w, const float* __restrict__ ln1_b,
    const float* __restrict__ eqn1_w, const float* __restrict__ eqn1_b,
    const float* __restrict__ inv_fc_w, const float* __restrict__ inv_fc_b,
    const float* __restrict__ equ_fc_w, const float* __restrict__ Winv,
    float* __restrict__ feats_ln, float* __restrict__ equ_ln,
    float* __restrict__ equ1t, float* __restrict__ PsP, float* __restrict__ PtP)
{
    __shared__ float fl_s[4][128];
    __shared__ float el_s[4][128];
    __shared__ float f1_s[4][32];
    const int w = threadIdx.x >> 6;
    const int lane = threadIdx.x & 63;
    const int n = blockIdx.x * 4 + w;
    const bool act = n < N;
    const int c = lane & 31;
    const int half = lane >> 5;

    // ---- feats LayerNorm ----
    float x0 = 0.f, x1 = 0.f;
    if (act) { x0 = feats[n * 128 + lane]; x1 = feats[n * 128 + 64 + lane]; }
    float s  = wsum64(x0 + x1);
    float sq = wsum64(x0 * x0 + x1 * x1);
    float mu = s * (1.f / 128.f);
    float var = sq * (1.f / 128.f) - mu * mu;
    float rs = rsqrtf(var + EPS);
    float y0 = (x0 - mu) * rs * ln1_w[lane] + ln1_b[lane];
    float y1 = (x1 - mu) * rs * ln1_w[64 + lane] + ln1_b[64 + lane];
    if (act) { feats_ln[n * 128 + lane] = y0; feats_ln[n * 128 + 64 + lane] = y1; }
    fl_s[w][lane] = y0; fl_s[w][64 + lane] = y1;

    // ---- equ layer norm ----
    float a = 0.f, b = 0.f;
    if (act) { a = equ[n * 128 + lane]; b = equ[n * 128 + 64 + lane]; }
    float a0 = (half == 0) ? a : 0.f;
    float m0 = wsum64(a0) * (1.f / 32.f);
    float f0 = a0 - m0;
    float n0 = wsum64((half == 0) ? f0 * f0 : 0.f) * (1.f / 32.f);
    float rs0 = rsqrtf(n0 + EPS);
    float sq1 = ((half == 1) ? a * a : 0.f) + b * b;
    float n1 = wsum64(sq1) * (1.f / 96.f);
    float rs1 = rsqrtf(n1 + EPS);
    float w1c = eqn1_w[32 + c];
    float ea = (half == 0) ? (f0 * rs0 * eqn1_w[c] + eqn1_b[c]) : (a * rs1 * w1c);
    float eb = b * rs1 * w1c;
    if (act) { equ_ln[n * 128 + lane] = ea; equ_ln[n * 128 + 64 + lane] = eb; }
    el_s[w][lane] = ea; el_s[w][64 + lane] = eb;

    __syncthreads();

    // ---- feats1: out[c] = sum_k fl[k]*W[k*32+c], K split across halves ----
    {
        float acc = 0.f;
#pragma unroll 8
        for (int k = 0; k < 64; k++) {
            int kk = half * 64 + k;
            acc += fl_s[w][kk] * inv_fc_w[kk * 32 + c];
        }
        acc += __shfl_xor(acc, 32);
        if (half == 0) f1_s[w][c] = acc + inv_fc_b[c];
    }
    // ---- equ1t: rows independent; lane handles (half, c) and (half+2, c) ----
    if (act) {
        float acc = 0.f, acc2 = 0.f;
#pragma unroll 8
        for (int k = 0; k < 32; k++) {
            float wv = equ_fc_w[k * 32 + c];
            acc  += el_s[w][half * 32 + k] * wv;
            acc2 += el_s[w][(half + 2) * 32 + k] * wv;
        }
        equ1t[n * 128 + c * 4 + half]     = acc;
        equ1t[n * 128 + c * 4 + half + 2] = acc2;
    }
    __syncthreads();
    if (!act) return;

    // ---- Ps/Pt: lane jj computes 4 consecutive outputs, K split by halves ----
    {
        const int jj = c;
        float4 aPs = {0.f, 0.f, 0.f, 0.f};
        float4 aPt = {0.f, 0.f, 0.f, 0.f};
#pragma unroll 4
        for (int k = 0; k < 16; k++) {
            int kk = half * 16 + k;
            float x = f1_s[w][kk];
            float4 w4 = *(const float4*)&Winv[kk * 128 + jj * 4];
            float4 v4 = *(const float4*)&Winv[(32 + kk) * 128 + jj * 4];
            aPs.x += x * w4.x; aPs.y += x * w4.y; aPs.z += x * w4.z; aPs.w += x * w4.w;
            aPt.x += x * v4.x; aPt.y += x * v4.y; aPt.z += x * v4.z; aPt.w += x * v4.w;
        }
        aPs.x += __shfl_xor(aPs.x, 32); aPs.y += __shfl_xor(aPs.y, 32);
        aPs.z += __shfl_xor(aPs.z, 32); aPs.w += __shfl_xor(aPs.w, 32);
        aPt.x += __shfl_xor(aPt.x, 32); aPt.y += __shfl_xor(aPt.y, 32);
        aPt.z += __shfl_xor(aPt.z, 32); aPt.w += __shfl_xor(aPt.w, 32);
        if (half == 0) {
            const float* ps = (const float*)&aPs;
            const float* pt = (const float*)&aPt;
#pragma unroll
            for (int i = 0; i < 4; i++) {
                int m = jj * 4 + i;
                PsP[n * 128 + (m & 31) * 4 + (m >> 5)] = ps[i];
                PtP[n * 128 + (m & 31) * 4 + (m >> 5)] = pt[i];
            }
        }
    }
}

// ---------------------------------------------------------------------------
// Kernel 2: per-edge messages + scatter-add. Half-wave per edge, 8 edges
// per 256-thread block. All LDS weight layouts packed for ds_read_b128.
// ---------------------------------------------------------------------------
__global__ __launch_bounds__(256) void edge_kernel(
    int E,
    const int* __restrict__ nb, const float* __restrict__ points,
    const float* __restrict__ equ1t, const float* __restrict__ PsP,
    const float* __restrict__ PtP,
    const float* __restrict__ Wl0g, const float* __restrict__ bl0g,
    const float* __restrict__ We2g, const float* __restrict__ Winvg,
    const float* __restrict__ binvg,
    float* __restrict__ inv_acc, float* __restrict__ equ_acc, float* __restrict__ cnt)
{
    __shared__ float WeP[32 * 128];   // WeP[k][c][j] = Winv[64+k][j*32+c]   16 KB
    __shared__ float Wl0P[16 * 128];  // Wl0P[g][c][i] = Wl0[g*4+i][c]        8 KB
    __shared__ float We2P[8 * 128];   // We2P[g][c][i] = We2[g*4+i][c]        4 KB
    __shared__ float BinvP[128];      // BinvP[c][j] = binv[j*32+c]
    __shared__ float bl0s[32];
    __shared__ float dots[8][64];
    __shared__ float amat[8][128];    // amat[slot][k][row]: {el0,s1,s2,s3}
    __shared__ float el0s[8][32];

    for (int idx = threadIdx.x; idx < 4096; idx += 256) {
        int k = idx >> 7, r = idx & 127, cc = r >> 2, j = r & 3;
        WeP[idx] = Winvg[(64 + k) * 128 + j * 32 + cc];
    }
    for (int idx = threadIdx.x; idx < 2048; idx += 256) {
        int g = idx >> 7, r = idx & 127, cc = r >> 2, i = r & 3;
        Wl0P[idx] = Wl0g[(g * 4 + i) * 32 + cc];
    }
    for (int idx = threadIdx.x; idx < 1024; idx += 256) {
        int g = idx >> 7, r = idx & 127, cc = r >> 2, i = r & 3;
        We2P[idx] = We2g[(g * 4 + i) * 32 + cc];
    }
    if (threadIdx.x < 128) BinvP[threadIdx.x] = binvg[(threadIdx.x & 3) * 32 + (threadIdx.x >> 2)];
    if (threadIdx.x < 32) bl0s[threadIdx.x] = bl0g[threadIdx.x];
    __syncthreads();

    const int slot = threadIdx.x >> 5;
    const int c = threadIdx.x & 31;
    const int nchunk = (E + 7) / 8;

    for (int chunk = blockIdx.x; chunk < nchunk; chunk += gridDim.x) {
        const int e = chunk * 8 + slot;
        const bool act = e < E;
        int dst = 0;
        float4 se4 = {0,0,0,0}, ps4 = {0,0,0,0}, pt4 = {0,0,0,0};
        if (act) {
            const int src = nb[e];
            dst = nb[E + e];
            se4 = *(const float4*)&equ1t[src * 128 + c * 4];
            float4 te4 = *(const float4*)&equ1t[dst * 128 + c * 4];
            ps4 = *(const float4*)&PsP[src * 128 + c * 4];
            pt4 = *(const float4*)&PtP[dst * 128 + c * 4];
            float sh1 = SQRT3F * (points[src * 3 + 0] - points[dst * 3 + 0]);
            float sh2 = SQRT3F * (points[src * 3 + 1] - points[dst * 3 + 1]);
            float sh3 = SQRT3F * (points[src * 3 + 2] - points[dst * 3 + 2]);
            dots[slot][c]      = se4.x * te4.x + se4.y * te4.y + se4.z * te4.z + se4.w * te4.w;
            dots[slot][32 + c] = se4.x + se4.y * sh1 + se4.z * sh2 + se4.w * sh3;
        }
        __syncthreads();
        if (act) {
            // equ_l0[c] = silu(b + sum_k dots[k] * Wl0[k][c])
            float acc = bl0s[c];
#pragma unroll
            for (int g = 0; g < 16; g++) {
                float4 d4 = *(const float4*)&dots[slot][g * 4];
                float4 w4 = *(const float4*)&Wl0P[g * 128 + c * 4];
                acc += d4.x * w4.x + d4.y * w4.y + d4.z * w4.z + d4.w * w4.w;
            }
            float el0 = siluf(acc);
            float4 arow = {el0, se4.y, se4.z, se4.w};
            *(float4*)&amat[slot][c * 4] = arow;
            el0s[slot][c] = el0;
        }
        __syncthreads();
        if (act) {
            // inv_message[j*32+c] = silu(binv + Ps[src] + Pt[dst] + el0 @ We)
            float4 m4 = *(const float4*)&BinvP[c * 4];
            m4.x += ps4.x + pt4.x; m4.y += ps4.y + pt4.y;
            m4.z += ps4.z + pt4.z; m4.w += ps4.w + pt4.w;
#pragma unroll
            for (int g = 0; g < 8; g++) {
                float4 x4 = *(const float4*)&el0s[slot][g * 4];
                const float* xp = (const float*)&x4;
#pragma unroll
                for (int i = 0; i < 4; i++) {
                    float4 w4 = *(const float4*)&WeP[(g * 4 + i) * 128 + c * 4];
                    float x = xp[i];
                    m4.x += x * w4.x; m4.y += x * w4.y; m4.z += x * w4.z; m4.w += x * w4.w;
                }
            }
            m4.x = siluf(m4.x); m4.y = siluf(m4.y); m4.z = siluf(m4.z); m4.w = siluf(m4.w);

            // equ_message rows: e_row[c] = sum_k amat[k][row] * We2[k][c]
            float e0 = 0.f, e1 = 0.f, e2 = 0.f, e3 = 0.f;
#pragma unroll
            for (int g = 0; g < 8; g++) {
                float4 w4 = *(const float4*)&We2P[g * 128 + c * 4];
                const float* wp = (const float*)&w4;
#pragma unroll
                for (int i = 0; i < 4; i++) {
                    float4 a4 = *(const float4*)&amat[slot][(g * 4 + i) * 4];
                    float wv = wp[i];
                    e0 += a4.x * wv; e1 += a4.y * wv; e2 += a4.z * wv; e3 += a4.w * wv;
                }
            }
            float mx = wmax32(fmaxf(fmaxf(m4.x, m4.y), fmaxf(m4.z, m4.w)));
            if (c == 0 && mx > 0.f) atomicAdd(&cnt[dst], 1.0f);
            float* ia = &inv_acc[dst * 128];
            atomicAdd(ia + c, m4.x); atomicAdd(ia + 32 + c, m4.y);
            atomicAdd(ia + 64 + c, m4.z); atomicAdd(ia + 96 + c, m4.w);
            float* ea = &equ_acc[dst * 128];
            atomicAdd(ea + c, e0); atomicAdd(ea + 32 + c, e1);
            atomicAdd(ea + 64 + c, e2); atomicAdd(ea + 96 + c, e3);
        }
        __syncthreads();
    }
}

// ---------------------------------------------------------------------------
// Kernel 3: per-node postprocessing. One wave per node, 4 nodes per block.
// FFN matvecs use float4 weight loads with K split across wave halves.
// ---------------------------------------------------------------------------
__global__ __launch_bounds__(256) void node_post(
    int N,
    const float* __restrict__ feats_ln, const float* __restrict__ equ_ln,
    const float* __restrict__ inv_acc, const float* __restrict__ equ_acc,
    const float* __restrict__ cnt,
    const float* __restrict__ ffn_ln_w, const float* __restrict__ ffn_ln_b,
    const float* __restrict__ W1, const float* __restrict__ b1,
    const float* __restrict__ W2, const float* __restrict__ b2,
    const float* __restrict__ eqn2_w, const float* __restrict__ eqn2_b,
    const float* __restrict__ fe1, const float* __restrict__ gate_w,
    const float* __restrict__ fe2,
    float* __restrict__ out_inv, float* __restrict__ out_equ)
{
    __shared__ float h_s[4][128];
    __shared__ float r_s[4][128];
    __shared__ float invs[4][128];
    __shared__ float e_s[4][128];
    __shared__ float g_s[4][128];
    __shared__ float aft_s[4][64];
    __shared__ float gg_s[4][128];

    const int w = threadIdx.x >> 6;
    const int lane = threadIdx.x & 63;
    const int n = blockIdx.x * 4 + w;
    const bool act = n < N;
    const int c = lane & 31;
    const int half = lane >> 5;

    float nbn = 1.f;
    if (act) nbn = 1.f + cnt[n];
    const float inv_nbn = 1.f / nbn;

    float inv0 = 0.f, inv1 = 0.f;
    if (act) {
        inv0 = (inv_acc[n * 128 + lane] + feats_ln[n * 128 + lane]) * inv_nbn;
        inv1 = (inv_acc[n * 128 + 64 + lane] + feats_ln[n * 128 + 64 + lane]) * inv_nbn;
    }
    invs[w][lane] = inv0; invs[w][64 + lane] = inv1;
    float s  = wsum64(inv0 + inv1);
    float sq = wsum64(inv0 * inv0 + inv1 * inv1);
    float mu = s * (1.f / 128.f);
    float var = sq * (1.f / 128.f) - mu * mu;
    float rs = rsqrtf(var + EPS);
    h_s[w][lane]      = (inv0 - mu) * rs * ffn_ln_w[lane] + ffn_ln_b[lane];
    h_s[w][64 + lane] = (inv1 - mu) * rs * ffn_ln_w[64 + lane] + ffn_ln_b[64 + lane];

    float en_a = 0.f, en_b = 0.f;
    if (act) {
        en_a = (equ_acc[n * 128 + lane] + equ_ln[n * 128 + lane]) * inv_nbn;
        en_b = (equ_acc[n * 128 + 64 + lane] + equ_ln[n * 128 + 64 + lane]) * inv_nbn;
    }
    float a0 = (half == 0) ? en_a : 0.f;
    float m0 = wsum64(a0) * (1.f / 32.f);
    float f0 = a0 - m0;
    float n0 = wsum64((half == 0) ? f0 * f0 : 0.f) * (1.f / 32.f);
    float rs0 = rsqrtf(n0 + EPS);
    float sq1 = ((half == 1) ? en_a * en_a : 0.f) + en_b * en_b;
    float n1 = wsum64(sq1) * (1.f / 96.f);
    float rs1 = rsqrtf(n1 + EPS);
    float w1c = eqn2_w[32 + c];
    e_s[w][lane]      = (half == 0) ? (f0 * rs0 * eqn2_w[c] + eqn2_b[c]) : (en_a * rs1 * w1c);
    e_s[w][64 + lane] = en_b * rs1 * w1c;

    __syncthreads();

    // FFN layer 1: lane jj owns outputs 4jj..4jj+3; halves split K
    {
        float4 acc = {0,0,0,0};
        const float* Wp = W1 + (size_t)(half * 64) * 128 + c * 4;
#pragma unroll 8
        for (int k = 0; k < 64; k++) {
            float x = h_s[w][half * 64 + k];
            float4 w4 = *(const float4*)(Wp + (size_t)k * 128);
            acc.x += x * w4.x; acc.y += x * w4.y; acc.z += x * w4.z; acc.w += x * w4.w;
        }
        acc.x += __shfl_xor(acc.x, 32); acc.y += __shfl_xor(acc.y, 32);
        acc.z += __shfl_xor(acc.z, 32); acc.w += __shfl_xor(acc.w, 32);
        if (half == 0) {
            float4 b4 = *(const float4*)&b1[c * 4];
            float4 r;
            r.x = fmaxf(acc.x + b4.x, 0.f); r.y = fmaxf(acc.y + b4.y, 0.f);
            r.z = fmaxf(acc.z + b4.z, 0.f); r.w = fmaxf(acc.w + b4.w, 0.f);
            *(float4*)&r_s[w][c * 4] = r;
        }
    }
    // g = eqn2_out @ fe1
    {
        float acc = 0.f, acc2 = 0.f;
#pragma unroll 8
        for (int k = 0; k < 32; k++) {
            float wv = fe1[k * 32 + c];
            acc  += e_s[w][half * 32 + k] * wv;
            acc2 += e_s[w][(half + 2) * 32 + k] * wv;
        }
        g_s[w][lane] = acc;
        g_s[w][64 + lane] = acc2;
    }
    __syncthreads();

    // FFN layer 2 + residual
    {
        float4 acc = {0,0,0,0};
        const float* Wp = W2 + (size_t)(half * 64) * 128 + c * 4;
#pragma unroll 8
        for (int k = 0; k < 64; k++) {
            float x = r_s[w][half * 64 + k];
            float4 w4 = *(const float4*)(Wp + (size_t)k * 128);
            acc.x += x * w4.x; acc.y += x * w4.y; acc.z += x * w4.z; acc.w += x * w4.w;
        }
        acc.x += __shfl_xor(acc.x, 32); acc.y += __shfl_xor(acc.y, 32);
        acc.z += __shfl_xor(acc.z, 32); acc.w += __shfl_xor(acc.w, 32);
        if (half == 0 && act) {
            float4 b4 = *(const float4*)&b2[c * 4];
            float4 r4 = *(const float4*)&invs[w][c * 4];
            float4 o;
            o.x = acc.x + b4.x + r4.x; o.y = acc.y + b4.y + r4.y;
            o.z = acc.z + b4.z + r4.z; o.w = acc.w + b4.w + r4.w;
            *(float4*)&out_inv[n * 128 + c * 4] = o;
        }
    }
    // gate pre-activation
    {
        float acc = 0.f;
#pragma unroll 8
        for (int k = 0; k < 32; k++) acc += g_s[w][k] * gate_w[k * 64 + lane];
        aft_s[w][lane] = acc;
    }
    __syncthreads();

    {
        float mult = sigm(aft_s[w][32 + c]);
        float G0 = (half == 0) ? siluf(aft_s[w][c]) : (g_s[w][32 + c] * mult);
        float G1 = g_s[w][64 + lane] * mult;
        gg_s[w][lane] = G0;
        gg_s[w][64 + lane] = G1;
    }
    __syncthreads();

    if (act) {
        float acc = 0.f, acc2 = 0.f;
#pragma unroll 8
        for (int k = 0; k < 32; k++) {
            float wv = fe2[k * 32 + c];
            acc  += gg_s[w][half * 32 + k] * wv;
            acc2 += gg_s[w][(half + 2) * 32 + k] * wv;
        }
        out_equ[n * 128 + lane] = acc + en_a;
        out_equ[n * 128 + 64 + lane] = acc2 + en_b;
    }
}

// ---------------------------------------------------------------------------
extern "C" void kernel_launch(void* const* d_in, const int* in_sizes, int n_in,
                              void* d_out, int out_size, void* d_ws, size_t ws_size,
                              hipStream_t stream)
{
    const float* feats     = (const float*)d_in[0];
    const float* equ       = (const float*)d_in[1];
    const float* points    = (const float*)d_in[2];
    const int*   neighbors = (const int*)d_in[3];
    const float* ln1_w     = (const float*)d_in[4];
    const float* ln1_b     = (const float*)d_in[5];
    const float* eqn1_w    = (const float*)d_in[6];
    const float* eqn1_b    = (const float*)d_in[7];
    const float* inv_fc_w  = (const float*)d_in[8];
    const float* inv_fc_b  = (const float*)d_in[9];
    const float* equ_fc_w  = (const float*)d_in[10];
    const float* fc_l0_w   = (const float*)d_in[11];
    const float* fc_l0_b   = (const float*)d_in[12];
    const float* equ_fc_2_w= (const float*)d_in[13];
    const float* inv_fc_1_w= (const float*)d_in[14];
    const float* inv_fc_1_b= (const float*)d_in[15];
    const float* ffn_ln_w  = (const float*)d_in[16];
    const float* ffn_ln_b  = (const float*)d_in[17];
    const float* ffn_w1    = (const float*)d_in[18];
    const float* ffn_b1    = (const float*)d_in[19];
    const float* ffn_w2    = (const float*)d_in[20];
    const float* ffn_b2    = (const float*)d_in[21];
    const float* eqn2_w    = (const float*)d_in[22];
    const float* eqn2_b    = (const float*)d_in[23];
    const float* fe1_w     = (const float*)d_in[24];
    const float* gate_w    = (const float*)d_in[25];
    const float* fe2_w     = (const float*)d_in[26];

    const int N = in_sizes[0] / 128;
    const int E = in_sizes[3] / 2;

    float* ws = (float*)d_ws;
    float* feats_ln = ws;                          // N*128
    float* equ_ln   = feats_ln + (size_t)N * 128;  // N*128
    float* equ1t    = equ_ln   + (size_t)N * 128;  // N*128
    float* PsP      = equ1t    + (size_t)N * 128;  // N*128
    float* PtP      = PsP      + (size_t)N * 128;  // N*128
    float* inv_acc  = PtP      + (size_t)N * 128;  // N*128 (zeroed)
    float* equ_acc  = inv_acc  + (size_t)N * 128;  // N*128 (zeroed)
    float* cnt      = equ_acc  + (size_t)N * 128;  // N     (zeroed)

    hipMemsetAsync(inv_acc, 0, (size_t)N * 257 * sizeof(float), stream);

    node_pre<<<(N + 3) / 4, 256, 0, stream>>>(
        N, feats, equ, ln1_w, ln1_b, eqn1_w, eqn1_b,
        inv_fc_w, inv_fc_b, equ_fc_w, inv_fc_1_w,
        feats_ln, equ_ln, equ1t, PsP, PtP);

    edge_kernel<<<1024, 256, 0, stream>>>(
        E, neighbors, points, equ1t, PsP, PtP,
        fc_l0_w, fc_l0_b, equ_fc_2_w, inv_fc_1_w, inv_fc_1_b,
        inv_acc, equ_acc, cnt);

    float* out_inv = (float*)d_out;
    float* out_equ = out_inv + (size_t)N * 128;
    node_post<<<(N + 3) / 4, 256, 0, stream>>>(
        N, feats_ln, equ_ln, inv_acc, equ_acc, cnt,
        ffn_ln_w, ffn_ln_b, ffn_w1, ffn_b1, ffn_w2, ffn_b2,
        eqn2_w, eqn2_b, fe1_w, gate_w, fe2_w,
        out_inv, out_equ);
}

// Round 3
// 512.513 us; speedup vs baseline: 1.6006x; 1.1493x over previous
//
#include <hip/hip_runtime.h>
#include <math.h>

#define EPS 1e-5f
#define SQRT3F 1.7320508075688772f

__device__ __forceinline__ float wsum64(float x) {
#pragma unroll
    for (int o = 32; o > 0; o >>= 1) x += __shfl_xor(x, o, 64);
    return x;
}
// reduction within a 32-lane half (offsets <32 never cross halves)
__device__ __forceinline__ float hsum32(float x) {
#pragma unroll
    for (int o = 16; o > 0; o >>= 1) x += __shfl_xor(x, o, 64);
    return x;
}
__device__ __forceinline__ float sigm(float x) { return 1.f / (1.f + __expf(-x)); }
__device__ __forceinline__ float siluf(float x) { return x * sigm(x); }

// ---------------------------------------------------------------------------
// Kernel 1: per-node preprocessing (same structure as R2).
// ---------------------------------------------------------------------------
__global__ __launch_bounds__(256) void node_pre(
    int N,
    const float* __restrict__ feats, const float* __restrict__ equ,
    const float* __restrict__ ln1_w, const float* __restrict__ ln1_b,
    const float* __restrict__ eqn1_w, const float* __restrict__ eqn1_b,
    const float* __restrict__ inv_fc_w, const float* __restrict__ inv_fc_b,
    const float* __restrict__ equ_fc_w, const float* __restrict__ Winv,
    float* __restrict__ feats_ln, float* __restrict__ equ_ln,
    float* __restrict__ equ1t, float* __restrict__ PsP, float* __restrict__ PtP)
{
    __shared__ float fl_s[4][128];
    __shared__ float el_s[4][128];
    __shared__ float f1_s[4][32];
    const int w = threadIdx.x >> 6;
    const int lane = threadIdx.x & 63;
    const int n = blockIdx.x * 4 + w;
    const bool act = n < N;
    const int c = lane & 31;
    const int half = lane >> 5;

    float x0 = 0.f, x1 = 0.f;
    if (act) { x0 = feats[n * 128 + lane]; x1 = feats[n * 128 + 64 + lane]; }
    float s  = wsum64(x0 + x1);
    float sq = wsum64(x0 * x0 + x1 * x1);
    float mu = s * (1.f / 128.f);
    float var = sq * (1.f / 128.f) - mu * mu;
    float rs = rsqrtf(var + EPS);
    float y0 = (x0 - mu) * rs * ln1_w[lane] + ln1_b[lane];
    float y1 = (x1 - mu) * rs * ln1_w[64 + lane] + ln1_b[64 + lane];
    if (act) { feats_ln[n * 128 + lane] = y0; feats_ln[n * 128 + 64 + lane] = y1; }
    fl_s[w][lane] = y0; fl_s[w][64 + lane] = y1;

    float a = 0.f, b = 0.f;
    if (act) { a = equ[n * 128 + lane]; b = equ[n * 128 + 64 + lane]; }
    float a0 = (half == 0) ? a : 0.f;
    float m0 = wsum64(a0) * (1.f / 32.f);
    float f0 = a0 - m0;
    float n0 = wsum64((half == 0) ? f0 * f0 : 0.f) * (1.f / 32.f);
    float rs0 = rsqrtf(n0 + EPS);
    float sq1 = ((half == 1) ? a * a : 0.f) + b * b;
    float n1 = wsum64(sq1) * (1.f / 96.f);
    float rs1 = rsqrtf(n1 + EPS);
    float w1c = eqn1_w[32 + c];
    float ea = (half == 0) ? (f0 * rs0 * eqn1_w[c] + eqn1_b[c]) : (a * rs1 * w1c);
    float eb = b * rs1 * w1c;
    if (act) { equ_ln[n * 128 + lane] = ea; equ_ln[n * 128 + 64 + lane] = eb; }
    el_s[w][lane] = ea; el_s[w][64 + lane] = eb;

    __syncthreads();

    {
        float acc = 0.f;
#pragma unroll 8
        for (int k = 0; k < 64; k++) {
            int kk = half * 64 + k;
            acc += fl_s[w][kk] * inv_fc_w[kk * 32 + c];
        }
        acc += __shfl_xor(acc, 32);
        if (half == 0) f1_s[w][c] = acc + inv_fc_b[c];
    }
    if (act) {
        float acc = 0.f, acc2 = 0.f;
#pragma unroll 8
        for (int k = 0; k < 32; k++) {
            float wv = equ_fc_w[k * 32 + c];
            acc  += el_s[w][half * 32 + k] * wv;
            acc2 += el_s[w][(half + 2) * 32 + k] * wv;
        }
        equ1t[n * 128 + c * 4 + half]     = acc;
        equ1t[n * 128 + c * 4 + half + 2] = acc2;
    }
    __syncthreads();
    if (!act) return;

    {
        const int jj = c;
        float4 aPs = {0.f, 0.f, 0.f, 0.f};
        float4 aPt = {0.f, 0.f, 0.f, 0.f};
#pragma unroll 4
        for (int k = 0; k < 16; k++) {
            int kk = half * 16 + k;
            float x = f1_s[w][kk];
            float4 w4 = *(const float4*)&Winv[kk * 128 + jj * 4];
            float4 v4 = *(const float4*)&Winv[(32 + kk) * 128 + jj * 4];
            aPs.x += x * w4.x; aPs.y += x * w4.y; aPs.z += x * w4.z; aPs.w += x * w4.w;
            aPt.x += x * v4.x; aPt.y += x * v4.y; aPt.z += x * v4.z; aPt.w += x * v4.w;
        }
        aPs.x += __shfl_xor(aPs.x, 32); aPs.y += __shfl_xor(aPs.y, 32);
        aPs.z += __shfl_xor(aPs.z, 32); aPs.w += __shfl_xor(aPs.w, 32);
        aPt.x += __shfl_xor(aPt.x, 32); aPt.y += __shfl_xor(aPt.y, 32);
        aPt.z += __shfl_xor(aPt.z, 32); aPt.w += __shfl_xor(aPt.w, 32);
        if (half == 0) {
            const float* ps = (const float*)&aPs;
            const float* pt = (const float*)&aPt;
#pragma unroll
            for (int i = 0; i < 4; i++) {
                int m = jj * 4 + i;
                PsP[n * 128 + (m & 31) * 4 + (m >> 5)] = ps[i];
                PtP[n * 128 + (m & 31) * 4 + (m >> 5)] = pt[i];
            }
        }
    }
}

// ---------------------------------------------------------------------------
// CSR build: histogram -> single-block scan -> scatter (src ids, dst-sorted)
// ---------------------------------------------------------------------------
__global__ __launch_bounds__(256) void csr_hist(int E, const int* __restrict__ nb,
                                                int* __restrict__ deg)
{
    int i = blockIdx.x * 256 + threadIdx.x;
    if (i < E) atomicAdd(&deg[nb[E + i]], 1);
}

__global__ __launch_bounds__(1024) void csr_scan(int N, const int* __restrict__ deg,
                                                 int* __restrict__ row_start,
                                                 int* __restrict__ cursor)
{
    __shared__ int part[1024];
    const int t = threadIdx.x;
    const int per = (N + 1023) / 1024;
    const int base = t * per;
    int s = 0;
    for (int i = 0; i < per; i++) { int idx = base + i; if (idx < N) s += deg[idx]; }
    part[t] = s;
    __syncthreads();
    for (int off = 1; off < 1024; off <<= 1) {
        int v = (t >= off) ? part[t - off] : 0;
        __syncthreads();
        part[t] += v;
        __syncthreads();
    }
    int run = (t > 0) ? part[t - 1] : 0;
    for (int i = 0; i < per; i++) {
        int idx = base + i;
        if (idx < N) { row_start[idx] = run; cursor[idx] = run; run += deg[idx]; }
    }
}

__global__ __launch_bounds__(256) void csr_scatter(int E, const int* __restrict__ nb,
                                                   int* __restrict__ cursor,
                                                   int* __restrict__ csr_src)
{
    int i = blockIdx.x * 256 + threadIdx.x;
    if (i < E) {
        int d = nb[E + i];
        int s = nb[i];
        int pos = atomicAdd(&cursor[d], 1);
        csr_src[pos] = s;
    }
}

// ---------------------------------------------------------------------------
// Kernel 2: per-DST aggregation. 32-lane group per dst (8 dsts/block).
// No atomics, no barriers in the loop (groups are half-waves). Edge pairs
// batched to halve weight LDS reads. equ-message matmul hoisted to epilogue.
// Writes inv_pre/equ_pre directly into d_out.
// ---------------------------------------------------------------------------
__global__ __launch_bounds__(256) void edge_agg(
    int N,
    const int* __restrict__ row_start, const int* __restrict__ deg_arr,
    const int* __restrict__ csr_src,
    const float* __restrict__ points, const float* __restrict__ equ1t,
    const float* __restrict__ PsP, const float* __restrict__ PtP,
    const float* __restrict__ feats_ln, const float* __restrict__ equ_ln,
    const float* __restrict__ Wl0g, const float* __restrict__ bl0g,
    const float* __restrict__ We2g, const float* __restrict__ Winvg,
    const float* __restrict__ binvg,
    float* __restrict__ out_inv, float* __restrict__ out_equ)
{
    __shared__ float WeP[32 * 128];   // [k][c][j] = Winv[64+k][j*32+c]
    __shared__ float Wl0P[16 * 128];  // [g][c][i] = Wl0[g*4+i][c]
    __shared__ float We2P[8 * 128];   // [g][c][i] = We2[g*4+i][c]
    __shared__ float BinvP[128];      // [c][j] = binv[j*32+c]
    __shared__ float bl0s[32];
    __shared__ float scr[8][128];     // per-group scratch: dots / el0 / amat

    for (int idx = threadIdx.x; idx < 4096; idx += 256) {
        int k = idx >> 7, r = idx & 127, cc = r >> 2, j = r & 3;
        WeP[idx] = Winvg[(64 + k) * 128 + j * 32 + cc];
    }
    for (int idx = threadIdx.x; idx < 2048; idx += 256) {
        int g = idx >> 7, r = idx & 127, cc = r >> 2, i = r & 3;
        Wl0P[idx] = Wl0g[(g * 4 + i) * 32 + cc];
    }
    for (int idx = threadIdx.x; idx < 1024; idx += 256) {
        int g = idx >> 7, r = idx & 127, cc = r >> 2, i = r & 3;
        We2P[idx] = We2g[(g * 4 + i) * 32 + cc];
    }
    if (threadIdx.x < 128) BinvP[threadIdx.x] = binvg[(threadIdx.x & 3) * 32 + (threadIdx.x >> 2)];
    if (threadIdx.x < 32) bl0s[threadIdx.x] = bl0g[threadIdx.x];
    __syncthreads();

    const int grp = threadIdx.x >> 5;
    const int c = threadIdx.x & 31;
    const int halfsel = grp & 1;      // which 32-bit half of the ballot mask
    const int n = blockIdx.x * 8 + grp;
    if (n >= N) return;

    const int start = row_start[n];
    const int len = deg_arr[n];
    float4 te4 = *(const float4*)&equ1t[n * 128 + c * 4];
    float4 pt4 = *(const float4*)&PtP[n * 128 + c * 4];
    const float pdx = points[n * 3 + 0], pdy = points[n * 3 + 1], pdz = points[n * 3 + 2];
    float4 base = *(const float4*)&BinvP[c * 4];
    base.x += pt4.x; base.y += pt4.y; base.z += pt4.z; base.w += pt4.w;

    float4 acc = {0.f, 0.f, 0.f, 0.f};   // inv message sum (cols 32j+c)
    float4 aer = {0.f, 0.f, 0.f, 0.f};   // sum of {el0, s1, s2, s3}[c]
    int cnt = 0;
    int i = 0;

    // ---- paired edge loop ----
    for (; i + 2 <= len; i += 2) {
        const int s0 = csr_src[start + i];
        const int s1 = csr_src[start + i + 1];
        float4 a0 = *(const float4*)&equ1t[s0 * 128 + c * 4];
        float4 a1 = *(const float4*)&equ1t[s1 * 128 + c * 4];
        float4 p0 = *(const float4*)&PsP[s0 * 128 + c * 4];
        float4 p1 = *(const float4*)&PsP[s1 * 128 + c * 4];
        float dx0 = SQRT3F * (points[s0 * 3 + 0] - pdx);
        float dy0 = SQRT3F * (points[s0 * 3 + 1] - pdy);
        float dz0 = SQRT3F * (points[s0 * 3 + 2] - pdz);
        float dx1 = SQRT3F * (points[s1 * 3 + 0] - pdx);
        float dy1 = SQRT3F * (points[s1 * 3 + 1] - pdy);
        float dz1 = SQRT3F * (points[s1 * 3 + 2] - pdz);
        scr[grp][c]      = a0.x * te4.x + a0.y * te4.y + a0.z * te4.z + a0.w * te4.w;
        scr[grp][32 + c] = a0.x + a0.y * dx0 + a0.z * dy0 + a0.w * dz0;
        scr[grp][64 + c] = a1.x * te4.x + a1.y * te4.y + a1.z * te4.z + a1.w * te4.w;
        scr[grp][96 + c] = a1.x + a1.y * dx1 + a1.z * dy1 + a1.w * dz1;

        float e0acc = bl0s[c], e1acc = bl0s[c];
#pragma unroll
        for (int g = 0; g < 16; g++) {
            float4 w4 = *(const float4*)&Wl0P[g * 128 + c * 4];
            float4 d0 = *(const float4*)&scr[grp][g * 4];
            float4 d1 = *(const float4*)&scr[grp][64 + g * 4];
            e0acc += d0.x * w4.x + d0.y * w4.y + d0.z * w4.z + d0.w * w4.w;
            e1acc += d1.x * w4.x + d1.y * w4.y + d1.z * w4.z + d1.w * w4.w;
        }
        float el0_0 = siluf(e0acc);
        float el0_1 = siluf(e1acc);
        aer.x += el0_0 + el0_1;
        aer.y += a0.y + a1.y; aer.z += a0.z + a1.z; aer.w += a0.w + a1.w;
        scr[grp][c] = el0_0;
        scr[grp][32 + c] = el0_1;

        float4 m0 = base, m1 = base;
        m0.x += p0.x; m0.y += p0.y; m0.z += p0.z; m0.w += p0.w;
        m1.x += p1.x; m1.y += p1.y; m1.z += p1.z; m1.w += p1.w;
#pragma unroll
        for (int g = 0; g < 8; g++) {
            float4 x0 = *(const float4*)&scr[grp][g * 4];
            float4 x1 = *(const float4*)&scr[grp][32 + g * 4];
            const float* xp0 = (const float*)&x0;
            const float* xp1 = (const float*)&x1;
#pragma unroll
            for (int t = 0; t < 4; t++) {
                float4 w4 = *(const float4*)&WeP[(g * 4 + t) * 128 + c * 4];
                float v0 = xp0[t], v1 = xp1[t];
                m0.x += v0 * w4.x; m0.y += v0 * w4.y; m0.z += v0 * w4.z; m0.w += v0 * w4.w;
                m1.x += v1 * w4.x; m1.y += v1 * w4.y; m1.z += v1 * w4.z; m1.w += v1 * w4.w;
            }
        }
        m0.x = siluf(m0.x); m0.y = siluf(m0.y); m0.z = siluf(m0.z); m0.w = siluf(m0.w);
        m1.x = siluf(m1.x); m1.y = siluf(m1.y); m1.z = siluf(m1.z); m1.w = siluf(m1.w);
        acc.x += m0.x + m1.x; acc.y += m0.y + m1.y;
        acc.z += m0.z + m1.z; acc.w += m0.w + m1.w;
        float mx0 = fmaxf(fmaxf(m0.x, m0.y), fmaxf(m0.z, m0.w));
        float mx1 = fmaxf(fmaxf(m1.x, m1.y), fmaxf(m1.z, m1.w));
        unsigned long long b0 = __ballot(mx0 > 0.f);
        unsigned long long b1 = __ballot(mx1 > 0.f);
        cnt += ((unsigned int)(b0 >> (halfsel * 32)) != 0u);
        cnt += ((unsigned int)(b1 >> (halfsel * 32)) != 0u);
    }
    // ---- tail ----
    for (; i < len; i++) {
        const int s0 = csr_src[start + i];
        float4 a0 = *(const float4*)&equ1t[s0 * 128 + c * 4];
        float4 p0 = *(const float4*)&PsP[s0 * 128 + c * 4];
        float dx0 = SQRT3F * (points[s0 * 3 + 0] - pdx);
        float dy0 = SQRT3F * (points[s0 * 3 + 1] - pdy);
        float dz0 = SQRT3F * (points[s0 * 3 + 2] - pdz);
        scr[grp][c]      = a0.x * te4.x + a0.y * te4.y + a0.z * te4.z + a0.w * te4.w;
        scr[grp][32 + c] = a0.x + a0.y * dx0 + a0.z * dy0 + a0.w * dz0;
        float e0acc = bl0s[c];
#pragma unroll
        for (int g = 0; g < 16; g++) {
            float4 w4 = *(const float4*)&Wl0P[g * 128 + c * 4];
            float4 d0 = *(const float4*)&scr[grp][g * 4];
            e0acc += d0.x * w4.x + d0.y * w4.y + d0.z * w4.z + d0.w * w4.w;
        }
        float el0_0 = siluf(e0acc);
        aer.x += el0_0; aer.y += a0.y; aer.z += a0.z; aer.w += a0.w;
        scr[grp][c] = el0_0;
        float4 m0 = base;
        m0.x += p0.x; m0.y += p0.y; m0.z += p0.z; m0.w += p0.w;
#pragma unroll
        for (int g = 0; g < 8; g++) {
            float4 x0 = *(const float4*)&scr[grp][g * 4];
            const float* xp0 = (const float*)&x0;
#pragma unroll
            for (int t = 0; t < 4; t++) {
                float4 w4 = *(const float4*)&WeP[(g * 4 + t) * 128 + c * 4];
                float v0 = xp0[t];
                m0.x += v0 * w4.x; m0.y += v0 * w4.y; m0.z += v0 * w4.z; m0.w += v0 * w4.w;
            }
        }
        m0.x = siluf(m0.x); m0.y = siluf(m0.y); m0.z = siluf(m0.z); m0.w = siluf(m0.w);
        acc.x += m0.x; acc.y += m0.y; acc.z += m0.z; acc.w += m0.w;
        float mx0 = fmaxf(fmaxf(m0.x, m0.y), fmaxf(m0.z, m0.w));
        unsigned long long b0 = __ballot(mx0 > 0.f);
        cnt += ((unsigned int)(b0 >> (halfsel * 32)) != 0u);
    }

    // ---- epilogue ----
    const float inv_nbn = 1.f / (1.f + (float)cnt);
    out_inv[n * 128 + c]      = (acc.x + feats_ln[n * 128 + c])      * inv_nbn;
    out_inv[n * 128 + 32 + c] = (acc.y + feats_ln[n * 128 + 32 + c]) * inv_nbn;
    out_inv[n * 128 + 64 + c] = (acc.z + feats_ln[n * 128 + 64 + c]) * inv_nbn;
    out_inv[n * 128 + 96 + c] = (acc.w + feats_ln[n * 128 + 96 + c]) * inv_nbn;

    *(float4*)&scr[grp][c * 4] = aer;   // amat[k][row]
    float4 eo = {0.f, 0.f, 0.f, 0.f};
#pragma unroll
    for (int g = 0; g < 8; g++) {
        float4 w4 = *(const float4*)&We2P[g * 128 + c * 4];
        const float* wp = (const float*)&w4;
#pragma unroll
        for (int t = 0; t < 4; t++) {
            float4 a4 = *(const float4*)&scr[grp][(g * 4 + t) * 4];
            float wv = wp[t];
            eo.x += a4.x * wv; eo.y += a4.y * wv; eo.z += a4.z * wv; eo.w += a4.w * wv;
        }
    }
    out_equ[n * 128 + c]      = (eo.x + equ_ln[n * 128 + c])      * inv_nbn;
    out_equ[n * 128 + 32 + c] = (eo.y + equ_ln[n * 128 + 32 + c]) * inv_nbn;
    out_equ[n * 128 + 64 + c] = (eo.z + equ_ln[n * 128 + 64 + c]) * inv_nbn;
    out_equ[n * 128 + 96 + c] = (eo.w + equ_ln[n * 128 + 96 + c]) * inv_nbn;
}

// ---------------------------------------------------------------------------
// Kernel 3: node_post. 32 nodes/block. Half-wave per node for LN/equ chain;
// wave handles 8 nodes for the FFN (W1/W2 read once per wave). In/out via
// d_out (inv_pre/equ_pre read then overwritten by the same threads).
// ---------------------------------------------------------------------------
__global__ __launch_bounds__(256) void node_post(
    int N,
    const float* __restrict__ ffn_ln_w, const float* __restrict__ ffn_ln_b,
    const float* __restrict__ W1g, const float* __restrict__ b1g,
    const float* __restrict__ W2g, const float* __restrict__ b2g,
    const float* __restrict__ eqn2_w, const float* __restrict__ eqn2_b,
    const float* __restrict__ fe1, const float* __restrict__ gate_w,
    const float* __restrict__ fe2,
    float* __restrict__ io_inv, float* __restrict__ io_equ)
{
    __shared__ float ht[128 * 36];     // h (then r) transposed: [row][node], pad 36
    __shared__ float es[8][128];       // per-group packed equ vectors [k*4+row]
    __shared__ float gs[8][128];
    __shared__ float fe1P[8 * 128];    // [g][c][i] = fe1[4g+i][c]
    __shared__ float fe2P[8 * 128];
    __shared__ float gatePa[8 * 128];  // [g][c][i] = gate_w[4g+i][c]
    __shared__ float gatePb[8 * 128];  // [g][c][i] = gate_w[4g+i][32+c]

    for (int idx = threadIdx.x; idx < 1024; idx += 256) {
        int g = idx >> 7, r = idx & 127, cc = r >> 2, i = r & 3;
        fe1P[idx]   = fe1[(g * 4 + i) * 32 + cc];
        fe2P[idx]   = fe2[(g * 4 + i) * 32 + cc];
        gatePa[idx] = gate_w[(g * 4 + i) * 64 + cc];
        gatePb[idx] = gate_w[(g * 4 + i) * 64 + 32 + cc];
    }
    __syncthreads();

    const int grp = threadIdx.x >> 5;
    const int c = threadIdx.x & 31;

    // ---- Phase A: half-wave per node, 4 nodes per group ----
    for (int q = 0; q < 4; q++) {
        const int nd = grp * 4 + q;
        const int n = blockIdx.x * 32 + nd;
        if (n >= N) break;

        // equ chain
        float eq0 = io_equ[n * 128 + c];
        float eq1 = io_equ[n * 128 + 32 + c];
        float eq2 = io_equ[n * 128 + 64 + c];
        float eq3 = io_equ[n * 128 + 96 + c];
        float m0 = hsum32(eq0) * (1.f / 32.f);
        float f0 = eq0 - m0;
        float n0 = hsum32(f0 * f0) * (1.f / 32.f);
        float rs0 = rsqrtf(n0 + EPS);
        float n1 = hsum32(eq1 * eq1 + eq2 * eq2 + eq3 * eq3) * (1.f / 96.f);
        float rs1 = rsqrtf(n1 + EPS);
        float w1c = eqn2_w[32 + c];
        float4 ev;
        ev.x = f0 * rs0 * eqn2_w[c] + eqn2_b[c];
        ev.y = eq1 * rs1 * w1c;
        ev.z = eq2 * rs1 * w1c;
        ev.w = eq3 * rs1 * w1c;
        *(float4*)&es[grp][c * 4] = ev;

        float4 g4 = {0.f, 0.f, 0.f, 0.f};
#pragma unroll
        for (int g = 0; g < 8; g++) {
            float4 w4 = *(const float4*)&fe1P[g * 128 + c * 4];
            const float* wp = (const float*)&w4;
#pragma unroll
            for (int t = 0; t < 4; t++) {
                float4 a4 = *(const float4*)&es[grp][(g * 4 + t) * 4];
                float wv = wp[t];
                g4.x += a4.x * wv; g4.y += a4.y * wv; g4.z += a4.z * wv; g4.w += a4.w * wv;
            }
        }
        *(float4*)&gs[grp][c * 4] = g4;

        float aftA = 0.f, aftB = 0.f;
#pragma unroll
        for (int g = 0; g < 8; g++) {
            float4 wa4 = *(const float4*)&gatePa[g * 128 + c * 4];
            float4 wb4 = *(const float4*)&gatePb[g * 128 + c * 4];
            const float* wap = (const float*)&wa4;
            const float* wbp = (const float*)&wb4;
#pragma unroll
            for (int t = 0; t < 4; t++) {
                float g0 = gs[grp][(g * 4 + t) * 4];   // row0 component
                aftA += g0 * wap[t];
                aftB += g0 * wbp[t];
            }
        }
        float mult = sigm(aftB);
        float4 G;
        G.x = siluf(aftA);
        G.y = g4.y * mult; G.z = g4.z * mult; G.w = g4.w * mult;
        *(float4*)&es[grp][c * 4] = G;   // reuse es

        float4 oo = {0.f, 0.f, 0.f, 0.f};
#pragma unroll
        for (int g = 0; g < 8; g++) {
            float4 w4 = *(const float4*)&fe2P[g * 128 + c * 4];
            const float* wp = (const float*)&w4;
#pragma unroll
            for (int t = 0; t < 4; t++) {
                float4 a4 = *(const float4*)&es[grp][(g * 4 + t) * 4];
                float wv = wp[t];
                oo.x += a4.x * wv; oo.y += a4.y * wv; oo.z += a4.z * wv; oo.w += a4.w * wv;
            }
        }
        io_equ[n * 128 + c]      = oo.x + eq0;
        io_equ[n * 128 + 32 + c] = oo.y + eq1;
        io_equ[n * 128 + 64 + c] = oo.z + eq2;
        io_equ[n * 128 + 96 + c] = oo.w + eq3;

        // h = LN(inv_pre) -> transposed LDS
        float ip0 = io_inv[n * 128 + c];
        float ip1 = io_inv[n * 128 + 32 + c];
        float ip2 = io_inv[n * 128 + 64 + c];
        float ip3 = io_inv[n * 128 + 96 + c];
        float sm = hsum32(ip0 + ip1 + ip2 + ip3) * (1.f / 128.f);
        float sv = hsum32(ip0 * ip0 + ip1 * ip1 + ip2 * ip2 + ip3 * ip3) * (1.f / 128.f) - sm * sm;
        float rsv = rsqrtf(sv + EPS);
        ht[c * 36 + nd]         = (ip0 - sm) * rsv * ffn_ln_w[c]      + ffn_ln_b[c];
        ht[(32 + c) * 36 + nd]  = (ip1 - sm) * rsv * ffn_ln_w[32 + c] + ffn_ln_b[32 + c];
        ht[(64 + c) * 36 + nd]  = (ip2 - sm) * rsv * ffn_ln_w[64 + c] + ffn_ln_b[64 + c];
        ht[(96 + c) * 36 + nd]  = (ip3 - sm) * rsv * ffn_ln_w[96 + c] + ffn_ln_b[96 + c];
    }

    // ---- Phase B: wave handles 8 nodes (its own groups' columns) ----
    const int wid = threadIdx.x >> 6;
    const int half = (threadIdx.x >> 5) & 1;
    const int ndbase = wid * 8;
    const int nbase = blockIdx.x * 32 + ndbase;

    float4 acc8[8];
#pragma unroll
    for (int j = 0; j < 8; j++) acc8[j] = make_float4(0.f, 0.f, 0.f, 0.f);
    for (int k = 0; k < 64; k++) {
        const int kk = half * 64 + k;
        float4 w4 = *(const float4*)&W1g[kk * 128 + c * 4];
        float4 xA = *(const float4*)&ht[kk * 36 + ndbase];
        float4 xB = *(const float4*)&ht[kk * 36 + ndbase + 4];
        const float* xa = (const float*)&xA;
        const float* xb = (const float*)&xB;
#pragma unroll
        for (int j = 0; j < 4; j++) {
            float v = xa[j];
            acc8[j].x += v * w4.x; acc8[j].y += v * w4.y; acc8[j].z += v * w4.z; acc8[j].w += v * w4.w;
            float u = xb[j];
            acc8[4 + j].x += u * w4.x; acc8[4 + j].y += u * w4.y; acc8[4 + j].z += u * w4.z; acc8[4 + j].w += u * w4.w;
        }
    }
#pragma unroll
    for (int j = 0; j < 8; j++) {
        acc8[j].x += __shfl_xor(acc8[j].x, 32); acc8[j].y += __shfl_xor(acc8[j].y, 32);
        acc8[j].z += __shfl_xor(acc8[j].z, 32); acc8[j].w += __shfl_xor(acc8[j].w, 32);
    }
    if (half == 0) {
        float4 b4 = *(const float4*)&b1g[c * 4];
#pragma unroll
        for (int j = 0; j < 8; j++) {
            float r0 = fmaxf(acc8[j].x + b4.x, 0.f);
            float r1 = fmaxf(acc8[j].y + b4.y, 0.f);
            float r2 = fmaxf(acc8[j].z + b4.z, 0.f);
            float r3 = fmaxf(acc8[j].w + b4.w, 0.f);
            ht[(4 * c + 0) * 36 + ndbase + j] = r0;
            ht[(4 * c + 1) * 36 + ndbase + j] = r1;
            ht[(4 * c + 2) * 36 + ndbase + j] = r2;
            ht[(4 * c + 3) * 36 + ndbase + j] = r3;
        }
    }
#pragma unroll
    for (int j = 0; j < 8; j++) acc8[j] = make_float4(0.f, 0.f, 0.f, 0.f);
    for (int k = 0; k < 64; k++) {
        const int kk = half * 64 + k;
        float4 w4 = *(const float4*)&W2g[kk * 128 + c * 4];
        float4 xA = *(const float4*)&ht[kk * 36 + ndbase];
        float4 xB = *(const float4*)&ht[kk * 36 + ndbase + 4];
        const float* xa = (const float*)&xA;
        const float* xb = (const float*)&xB;
#pragma unroll
        for (int j = 0; j < 4; j++) {
            float v = xa[j];
            acc8[j].x += v * w4.x; acc8[j].y += v * w4.y; acc8[j].z += v * w4.z; acc8[j].w += v * w4.w;
            float u = xb[j];
            acc8[4 + j].x += u * w4.x; acc8[4 + j].y += u * w4.y; acc8[4 + j].z += u * w4.z; acc8[4 + j].w += u * w4.w;
        }
    }
#pragma unroll
    for (int j = 0; j < 8; j++) {
        acc8[j].x += __shfl_xor(acc8[j].x, 32); acc8[j].y += __shfl_xor(acc8[j].y, 32);
        acc8[j].z += __shfl_xor(acc8[j].z, 32); acc8[j].w += __shfl_xor(acc8[j].w, 32);
    }
    if (half == 0) {
        float4 b4 = *(const float4*)&b2g[c * 4];
#pragma unroll
        for (int j = 0; j < 8; j++) {
            const int n = nbase + j;
            if (n < N) {
                float4 ipre = *(const float4*)&io_inv[n * 128 + c * 4];
                float4 o;
                o.x = acc8[j].x + b4.x + ipre.x;
                o.y = acc8[j].y + b4.y + ipre.y;
                o.z = acc8[j].z + b4.z + ipre.z;
                o.w = acc8[j].w + b4.w + ipre.w;
                *(float4*)&io_inv[n * 128 + c * 4] = o;
            }
        }
    }
}

// ---------------------------------------------------------------------------
extern "C" void kernel_launch(void* const* d_in, const int* in_sizes, int n_in,
                              void* d_out, int out_size, void* d_ws, size_t ws_size,
                              hipStream_t stream)
{
    const float* feats     = (const float*)d_in[0];
    const float* equ       = (const float*)d_in[1];
    const float* points    = (const float*)d_in[2];
    const int*   neighbors = (const int*)d_in[3];
    const float* ln1_w     = (const float*)d_in[4];
    const float* ln1_b     = (const float*)d_in[5];
    const float* eqn1_w    = (const float*)d_in[6];
    const float* eqn1_b    = (const float*)d_in[7];
    const float* inv_fc_w  = (const float*)d_in[8];
    const float* inv_fc_b  = (const float*)d_in[9];
    const float* equ_fc_w  = (const float*)d_in[10];
    const float* fc_l0_w   = (const float*)d_in[11];
    const float* fc_l0_b   = (const float*)d_in[12];
    const float* equ_fc_2_w= (const float*)d_in[13];
    const float* inv_fc_1_w= (const float*)d_in[14];
    const float* inv_fc_1_b= (const float*)d_in[15];
    const float* ffn_ln_w  = (const float*)d_in[16];
    const float* ffn_ln_b  = (const float*)d_in[17];
    const float* ffn_w1    = (const float*)d_in[18];
    const float* ffn_b1    = (const float*)d_in[19];
    const float* ffn_w2    = (const float*)d_in[20];
    const float* ffn_b2    = (const float*)d_in[21];
    const float* eqn2_w    = (const float*)d_in[22];
    const float* eqn2_b    = (const float*)d_in[23];
    const float* fe1_w     = (const float*)d_in[24];
    const float* gate_w    = (const float*)d_in[25];
    const float* fe2_w     = (const float*)d_in[26];

    const int N = in_sizes[0] / 128;
    const int E = in_sizes[3] / 2;

    float* ws = (float*)d_ws;
    float* feats_ln = ws;                          // N*128
    float* equ_ln   = feats_ln + (size_t)N * 128;
    float* equ1t    = equ_ln   + (size_t)N * 128;
    float* PsP      = equ1t    + (size_t)N * 128;
    float* PtP      = PsP      + (size_t)N * 128;
    int* deg        = (int*)(PtP + (size_t)N * 128);   // N
    int* row_start  = deg + N;                          // N
    int* cursor     = row_start + N;                    // N
    int* csr_src    = cursor + N;                       // E

    hipMemsetAsync(deg, 0, (size_t)N * sizeof(int), stream);

    node_pre<<<(N + 3) / 4, 256, 0, stream>>>(
        N, feats, equ, ln1_w, ln1_b, eqn1_w, eqn1_b,
        inv_fc_w, inv_fc_b, equ_fc_w, inv_fc_1_w,
        feats_ln, equ_ln, equ1t, PsP, PtP);

    csr_hist<<<(E + 255) / 256, 256, 0, stream>>>(E, neighbors, deg);
    csr_scan<<<1, 1024, 0, stream>>>(N, deg, row_start, cursor);
    csr_scatter<<<(E + 255) / 256, 256, 0, stream>>>(E, neighbors, cursor, csr_src);

    float* out_inv = (float*)d_out;
    float* out_equ = out_inv + (size_t)N * 128;

    edge_agg<<<(N + 7) / 8, 256, 0, stream>>>(
        N, row_start, deg, csr_src,
        points, equ1t, PsP, PtP, feats_ln, equ_ln,
        fc_l0_w, fc_l0_b, equ_fc_2_w, inv_fc_1_w, inv_fc_1_b,
        out_inv, out_equ);

    node_post<<<(N + 31) / 32, 256, 0, stream>>>(
        N, ffn_ln_w, ffn_ln_b, ffn_w1, ffn_b1, ffn_w2, ffn_b2,
        eqn2_w, eqn2_b, fe1_w, gate_w, fe2_w,
        out_inv, out_equ);
}